// Round 1
// baseline (1507.086 us; speedup 1.0000x reference)
//
#include <hip/hip_runtime.h>
#include <math.h>

// Problem constants (N,C,H,W) = (16,128,128,128)
#define CN      128
#define HWN     16384          // H*W = 128*128
#define NBATCH  16

// ---------------------------------------------------------------------------
// Phase A: k/q/v = 1x1 conv (einsum 'nchw,oc->nohw' + bias), all three fused.
// One thread per (n, hw). 8-wide output-channel blocking x 3 tensors = 24 acc.
// Weight reads are wave-uniform -> scalar loads; x reads coalesced dwords.
// ---------------------------------------------------------------------------
__global__ __launch_bounds__(256) void kqv_kernel(
    const float* __restrict__ x,
    const float* __restrict__ wk, const float* __restrict__ bk,
    const float* __restrict__ wq, const float* __restrict__ bq,
    const float* __restrict__ wv, const float* __restrict__ bv,
    float* __restrict__ kbuf, float* __restrict__ qbuf, float* __restrict__ vbuf)
{
    const int n  = blockIdx.y;
    const int hw = blockIdx.x * 256 + threadIdx.x;
    const float* xp = x + (size_t)n * CN * HWN + hw;

    for (int og = 0; og < 16; ++og) {
        float ak[8], aq[8], av[8];
        #pragma unroll
        for (int j = 0; j < 8; ++j) {
            const int o = og * 8 + j;
            ak[j] = bk[o];
            aq[j] = bq[o];
            av[j] = bv[o];
        }
        // x column re-read per og (16x) is served by L1/L2 (128 KiB/block).
        for (int c = 0; c < CN; ++c) {
            const float xv = xp[(size_t)c * HWN];
            #pragma unroll
            for (int j = 0; j < 8; ++j) {
                const int o = og * 8 + j;
                ak[j] = fmaf(wk[o * CN + c], xv, ak[j]);
                aq[j] = fmaf(wq[o * CN + c], xv, aq[j]);
                av[j] = fmaf(wv[o * CN + c], xv, av[j]);
            }
        }
        #pragma unroll
        for (int j = 0; j < 8; ++j) {
            const int o = og * 8 + j;
            const size_t oi = (size_t)(n * CN + o) * HWN + hw;
            kbuf[oi] = ak[j];
            qbuf[oi] = aq[j];
            vbuf[oi] = av[j];
        }
    }
}

// ---------------------------------------------------------------------------
// Phase B: per (n,o): S = K^T Q / sqrt(C); A = softmax over w (first index);
// O = V A; out = gamma*O + x.  One 256-thread block per (n,o).
//
// S lives in exactly 64 KiB LDS as S[w][v] (no padding). Lane-interleaved
// v-mapping (v = (t&15) + 16*j) makes every LDS access <=2-way bank aliased
// (free on gfx950); softmax lane v=t hits 32 distinct banks.
// ---------------------------------------------------------------------------
__global__ __launch_bounds__(256) void attn_kernel(
    const float* __restrict__ kbuf, const float* __restrict__ qbuf,
    const float* __restrict__ vbuf, const float* __restrict__ x,
    const float* __restrict__ gamma, float* __restrict__ out)
{
    __shared__ float S[128][128];   // S[w][v], 64 KiB exactly

    const int no = blockIdx.x;      // n*128 + o
    const float* Kp = kbuf + (size_t)no * HWN;
    const float* Qp = qbuf + (size_t)no * HWN;
    const float* Vp = vbuf + (size_t)no * HWN;

    const int t  = threadIdx.x;
    const int tl = t & 15;          // lane-within-group: v interleave base
    const int tg = t >> 4;          // group 0..15: w/h tile base

    // ---- S[w][v] = (1/sqrt(128)) * sum_h K[h][w] * Q[h][v] ----
    {
        const int w0 = tg * 8;
        float acc[8][8];
        #pragma unroll
        for (int i = 0; i < 8; ++i)
            #pragma unroll
            for (int j = 0; j < 8; ++j) acc[i][j] = 0.0f;

        for (int h = 0; h < 128; ++h) {
            const float4 k0 = *(const float4*)(Kp + h * 128 + w0);
            const float4 k1 = *(const float4*)(Kp + h * 128 + w0 + 4);
            float kr[8] = {k0.x, k0.y, k0.z, k0.w, k1.x, k1.y, k1.z, k1.w};
            float qr[8];
            #pragma unroll
            for (int j = 0; j < 8; ++j) qr[j] = Qp[h * 128 + tl + 16 * j];
            #pragma unroll
            for (int i = 0; i < 8; ++i)
                #pragma unroll
                for (int j = 0; j < 8; ++j)
                    acc[i][j] = fmaf(kr[i], qr[j], acc[i][j]);
        }
        const float sc = 0.08838834764831845f;  // 1/sqrt(128)
        #pragma unroll
        for (int i = 0; i < 8; ++i)
            #pragma unroll
            for (int j = 0; j < 8; ++j)
                S[w0 + i][tl + 16 * j] = acc[i][j] * sc;   // 2-way bank alias: free
    }
    __syncthreads();

    // ---- column softmax over w (axis=2 of sim) ----
    if (t < 128) {
        const int v = t;                         // bank = t%32: conflict-free
        float m = -INFINITY;
        for (int w = 0; w < 128; ++w) m = fmaxf(m, S[w][v]);
        float s = 0.0f;
        for (int w = 0; w < 128; ++w) {
            const float e = __expf(S[w][v] - m);
            S[w][v] = e;
            s += e;
        }
        const float inv = 1.0f / s;
        for (int w = 0; w < 128; ++w) S[w][v] *= inv;
    }
    __syncthreads();

    // ---- O[h][v] = sum_w V[h][w] * A[w][v];  out = gamma*O + x ----
    {
        const int h0 = tg * 8;
        float acc[8][8];
        #pragma unroll
        for (int i = 0; i < 8; ++i)
            #pragma unroll
            for (int j = 0; j < 8; ++j) acc[i][j] = 0.0f;

        for (int w = 0; w < 128; w += 4) {
            float4 vv[8];
            #pragma unroll
            for (int i = 0; i < 8; ++i)
                vv[i] = *(const float4*)(Vp + (h0 + i) * 128 + w);
            #pragma unroll
            for (int ww = 0; ww < 4; ++ww) {
                float ar[8];
                #pragma unroll
                for (int j = 0; j < 8; ++j) ar[j] = S[w + ww][tl + 16 * j];
                #pragma unroll
                for (int i = 0; i < 8; ++i) {
                    const float vvw = ((const float*)&vv[i])[ww];
                    #pragma unroll
                    for (int j = 0; j < 8; ++j)
                        acc[i][j] = fmaf(vvw, ar[j], acc[i][j]);
                }
            }
        }

        const float g = gamma[0];
        const float* xp = x + (size_t)no * HWN;
        float*       op = out + (size_t)no * HWN;
        #pragma unroll
        for (int i = 0; i < 8; ++i) {
            #pragma unroll
            for (int j = 0; j < 8; ++j) {
                const int idx = (h0 + i) * 128 + tl + 16 * j;
                op[idx] = fmaf(g, acc[i][j], xp[idx]);
            }
        }
    }
}

// ---------------------------------------------------------------------------
extern "C" void kernel_launch(void* const* d_in, const int* in_sizes, int n_in,
                              void* d_out, int out_size, void* d_ws, size_t ws_size,
                              hipStream_t stream) {
    const float* x     = (const float*)d_in[0];
    const float* wk    = (const float*)d_in[1];
    const float* bk    = (const float*)d_in[2];
    const float* wq    = (const float*)d_in[3];
    const float* bq    = (const float*)d_in[4];
    const float* wv    = (const float*)d_in[5];
    const float* bv    = (const float*)d_in[6];
    const float* gamma = (const float*)d_in[7];
    float* out = (float*)d_out;

    // Workspace: k, q, v in fp32, 128 MiB each (384 MiB total).
    const size_t tsz = (size_t)NBATCH * CN * HWN;
    float* kbuf = (float*)d_ws;
    float* qbuf = kbuf + tsz;
    float* vbuf = qbuf + tsz;

    dim3 gA(HWN / 256, NBATCH);
    kqv_kernel<<<gA, 256, 0, stream>>>(x, wk, bk, wq, bq, wv, bv, kbuf, qbuf, vbuf);
    attn_kernel<<<NBATCH * CN, 256, 0, stream>>>(kbuf, qbuf, vbuf, x, gamma, out);
}

// Round 2
// 1048.369 us; speedup vs baseline: 1.4376x; 1.4376x over previous
//
#include <hip/hip_runtime.h>
#include <hip/hip_bf16.h>
#include <math.h>

// Problem constants (N,C,H,W) = (16,128,128,128)
#define CN      128
#define HWN     16384          // H*W
#define NBATCH  16
#define PLANE   (CN * HWN)     // 2097152 elems per (n) per tensor
#define TSTRIDE ((size_t)NBATCH * PLANE)   // 33554432 elems per tensor in kqv buf

__device__ __forceinline__ float bf2f(unsigned short u) {
    union { unsigned int i; float f; } x; x.i = ((unsigned int)u) << 16; return x.f;
}

// ---------------------------------------------------------------------------
// Prep: transpose+concat weights into Wt[c][384] (o' = tensor*128 + o) and
// append bias row at c=128. 198144 B, runs once, ~3 us.
// ---------------------------------------------------------------------------
__global__ void prep_kernel(const float* __restrict__ wk, const float* __restrict__ bk,
                            const float* __restrict__ wq, const float* __restrict__ bq,
                            const float* __restrict__ wv, const float* __restrict__ bv,
                            float* __restrict__ Wt)
{
    int i = blockIdx.x * 256 + threadIdx.x;
    if (i < 3 * CN * CN) {
        int tensor = i >> 14, o = (i >> 7) & 127, c = i & 127;
        const float* w = tensor == 0 ? wk : (tensor == 1 ? wq : wv);
        Wt[c * 384 + tensor * CN + o] = w[o * CN + c];
    }
    if (i < 384) {
        const float* b = i < 128 ? bk : (i < 256 ? bq : bv);
        Wt[CN * 384 + i] = b[i & 127];
    }
}

// ---------------------------------------------------------------------------
// Phase A: k/q/v 1x1 convs. Block = 256 thr, tile = 128 hw positions.
// x tile staged in LDS ONCE (64 KiB), then 16 og-groups of 24 output rows
// stream weights from Wt via wave-uniform s_loads. Threads t<128 do og 0..7,
// t>=128 do og 8..15 (half via readfirstlane -> provably wave-uniform).
// Outputs stored bf16 to kqv[tensor][n][ch][hw].
// ---------------------------------------------------------------------------
__global__ __launch_bounds__(256) void kqv_kernel(
    const float* __restrict__ x, const float* __restrict__ Wt,
    __hip_bfloat16* __restrict__ kqv)
{
    __shared__ float X[32][512];   // [c/4][hw*4 + c%4], 64 KiB

    const int n   = blockIdx.y;
    const int hw0 = blockIdx.x * 128;
    const int t   = threadIdx.x;

    // ---- stage x tile: coalesced dword reads, 8-way-bank LDS writes (cheap)
    const float* xn = x + (size_t)n * PLANE + hw0;
    for (int r = 0; r < 64; ++r) {
        int e = r * 256 + t;
        int c = e >> 7, hw = e & 127;
        X[c >> 2][hw * 4 + (c & 3)] = xn[(size_t)c * HWN + hw];
    }
    __syncthreads();

    const int half = __builtin_amdgcn_readfirstlane(t >> 7);  // 0 or 1, wave-uniform
    const int hwl  = t & 127;

    for (int og = 0; og < 8; ++og) {
        const int ob = (half * 8 + og) * 24;   // output-row base, 0..360
        float acc[24];
        #pragma unroll
        for (int j = 0; j < 24; ++j) acc[j] = Wt[CN * 384 + ob + j];  // bias

        for (int c4 = 0; c4 < 32; ++c4) {
            const float4 xv = *(const float4*)&X[c4][hwl * 4];
            const float* wr = Wt + (c4 * 4) * 384 + ob;
            #pragma unroll
            for (int cc = 0; cc < 4; ++cc) {
                const float xs = ((const float*)&xv)[cc];
                #pragma unroll
                for (int j = 0; j < 24; ++j)
                    acc[j] = fmaf(wr[cc * 384 + j], xs, acc[j]);
            }
        }

        #pragma unroll
        for (int j = 0; j < 24; ++j) {
            const int op = ob + j;             // 0..383
            const size_t idx = ((size_t)(op >> 7) * NBATCH + n) * PLANE
                             + (size_t)(op & 127) * HWN + hw0 + hwl;
            kqv[idx] = __float2bfloat16(acc[j]);
        }
    }
}

// ---------------------------------------------------------------------------
// Phase B: per (n,o): S = K^T Q / sqrt(C); softmax over w; O = V A;
// out = gamma*O + x. One 256-thread block per (n,o). S = 64 KiB LDS.
// K/Q h-chunks double-buffered in an 8 KiB window ALIASED into S (S is
// written only after the h-loop, so total LDS stays 64 KiB -> 2 blocks/CU).
// Thread (tl,tg): rows w0=tg*8, cols v0=tl*8 (contiguous -> 16 B loads).
// ---------------------------------------------------------------------------
__global__ __launch_bounds__(256) void attn_kernel(
    const __hip_bfloat16* __restrict__ kqv, const float* __restrict__ x,
    const float* __restrict__ gamma, float* __restrict__ out)
{
    __shared__ float S[128][128];   // 64 KiB

    const int no = blockIdx.x;
    const size_t plane = (size_t)no * HWN;
    const unsigned short* Kp = (const unsigned short*)kqv + plane;
    const unsigned short* Qp = (const unsigned short*)kqv + TSTRIDE + plane;
    const unsigned short* Vp = (const unsigned short*)kqv + 2 * TSTRIDE + plane;

    const int t  = threadIdx.x;
    const int tl = t & 15, tg = t >> 4;
    const int w0 = tg * 8;          // S rows    (also h rows in O-phase)
    const int v0 = tl * 8;          // S columns

    // ---- S-phase: S[w][v] = sum_h K[h][w]*Q[h][v], acc in registers ----
    float acc[8][8];
    #pragma unroll
    for (int i = 0; i < 8; ++i)
        #pragma unroll
        for (int j = 0; j < 8; ++j) acc[i][j] = 0.0f;

    unsigned short* KQ = (unsigned short*)&S[0][0];  // [buf2][K/Q][1024] = 8 KiB

    { // stage chunk 0
        *(ushort4*)&KQ[t * 4]        = *(const ushort4*)&Kp[t * 4];
        *(ushort4*)&KQ[1024 + t * 4] = *(const ushort4*)&Qp[t * 4];
    }
    __syncthreads();

    for (int hc = 0; hc < 16; ++hc) {
        const int cur = (hc & 1) * 2048, nxt = cur ^ 2048;
        if (hc < 15) {  // prefetch next chunk into the other buffer
            *(ushort4*)&KQ[nxt + t * 4]        = *(const ushort4*)&Kp[(hc + 1) * 1024 + t * 4];
            *(ushort4*)&KQ[nxt + 1024 + t * 4] = *(const ushort4*)&Qp[(hc + 1) * 1024 + t * 4];
        }
        const unsigned short* Kl = &KQ[cur];
        const unsigned short* Ql = &KQ[cur + 1024];
        #pragma unroll
        for (int i = 0; i < 8; ++i) {
            const ushort4 ka = *(const ushort4*)&Kl[i * 128 + w0];
            const ushort4 kb = *(const ushort4*)&Kl[i * 128 + w0 + 4];
            const ushort4 qa = *(const ushort4*)&Ql[i * 128 + v0];
            const ushort4 qb = *(const ushort4*)&Ql[i * 128 + v0 + 4];
            const float kr[8] = {bf2f(ka.x), bf2f(ka.y), bf2f(ka.z), bf2f(ka.w),
                                 bf2f(kb.x), bf2f(kb.y), bf2f(kb.z), bf2f(kb.w)};
            const float qr[8] = {bf2f(qa.x), bf2f(qa.y), bf2f(qa.z), bf2f(qa.w),
                                 bf2f(qb.x), bf2f(qb.y), bf2f(qb.z), bf2f(qb.w)};
            #pragma unroll
            for (int ii = 0; ii < 8; ++ii)
                #pragma unroll
                for (int j = 0; j < 8; ++j)
                    acc[ii][j] = fmaf(kr[ii], qr[j], acc[ii][j]);
        }
        __syncthreads();
    }

    // ---- spill S (staging window is dead now) ----
    const float sc = 0.08838834764831845f;   // 1/sqrt(128)
    #pragma unroll
    for (int i = 0; i < 8; ++i)
        #pragma unroll
        for (int j = 0; j < 8; ++j)
            S[w0 + i][v0 + j] = acc[i][j] * sc;
    __syncthreads();

    // ---- column softmax over w ----
    if (t < 128) {
        const int v = t;
        float m = -INFINITY;
        for (int w = 0; w < 128; ++w) m = fmaxf(m, S[w][v]);
        float s = 0.0f;
        for (int w = 0; w < 128; ++w) {
            const float e = __expf(S[w][v] - m);
            S[w][v] = e;
            s += e;
        }
        const float inv = 1.0f / s;
        for (int w = 0; w < 128; ++w) S[w][v] *= inv;
    }
    __syncthreads();

    // ---- O[h][v] = sum_w V[h][w]*A[w][v]; out = gamma*O + x ----
    const int h0 = w0;
    float oacc[8][8];
    #pragma unroll
    for (int i = 0; i < 8; ++i)
        #pragma unroll
        for (int j = 0; j < 8; ++j) oacc[i][j] = 0.0f;

    for (int w8 = 0; w8 < 128; w8 += 8) {
        uint4 vv[8];
        #pragma unroll
        for (int i = 0; i < 8; ++i)
            vv[i] = *(const uint4*)&Vp[(h0 + i) * 128 + w8];   // 8 bf16
        #pragma unroll
        for (int ww = 0; ww < 8; ++ww) {
            const float4 a0 = *(const float4*)&S[w8 + ww][v0];
            const float4 a1 = *(const float4*)&S[w8 + ww][v0 + 4];
            const float ar[8] = {a0.x, a0.y, a0.z, a0.w, a1.x, a1.y, a1.z, a1.w};
            #pragma unroll
            for (int i = 0; i < 8; ++i) {
                const float vw = bf2f(((const unsigned short*)&vv[i])[ww]);
                #pragma unroll
                for (int j = 0; j < 8; ++j)
                    oacc[i][j] = fmaf(vw, ar[j], oacc[i][j]);
            }
        }
    }

    const float g = gamma[0];
    const float* xp = x + plane;
    float*       op = out + plane;
    #pragma unroll
    for (int i = 0; i < 8; ++i) {
        #pragma unroll
        for (int j4 = 0; j4 < 8; j4 += 4) {
            const int idx = (h0 + i) * 128 + v0 + j4;
            float4 xv = *(const float4*)&xp[idx];
            float4 r;
            r.x = fmaf(g, oacc[i][j4 + 0], xv.x);
            r.y = fmaf(g, oacc[i][j4 + 1], xv.y);
            r.z = fmaf(g, oacc[i][j4 + 2], xv.z);
            r.w = fmaf(g, oacc[i][j4 + 3], xv.w);
            *(float4*)&op[idx] = r;
        }
    }
}

// ---------------------------------------------------------------------------
extern "C" void kernel_launch(void* const* d_in, const int* in_sizes, int n_in,
                              void* d_out, int out_size, void* d_ws, size_t ws_size,
                              hipStream_t stream) {
    const float* x     = (const float*)d_in[0];
    const float* wk    = (const float*)d_in[1];
    const float* bk    = (const float*)d_in[2];
    const float* wq    = (const float*)d_in[3];
    const float* bq    = (const float*)d_in[4];
    const float* wv    = (const float*)d_in[5];
    const float* bv    = (const float*)d_in[6];
    const float* gamma = (const float*)d_in[7];
    float* out = (float*)d_out;

    // ws layout: Wt (129x384 fp32, padded to 256 KiB) | kqv bf16 (192 MiB)
    float* Wt = (float*)d_ws;
    __hip_bfloat16* kqv = (__hip_bfloat16*)((char*)d_ws + (256 << 10));

    prep_kernel<<<192, 256, 0, stream>>>(wk, bk, wq, bq, wv, bv, Wt);
    dim3 gA(HWN / 128, NBATCH);
    kqv_kernel<<<gA, 256, 0, stream>>>(x, Wt, kqv);
    attn_kernel<<<NBATCH * CN, 256, 0, stream>>>(kqv, x, gamma, out);
}

// Round 3
// 429.119 us; speedup vs baseline: 3.5120x; 2.4431x over previous
//
#include <hip/hip_runtime.h>
#include <hip/hip_bf16.h>
#include <math.h>

// Problem constants (N,C,H,W) = (16,128,128,128)
#define CN      128
#define HWN     16384
#define NBATCH  16
#define PLANE   (CN * HWN)
#define TSTRIDE ((size_t)NBATCH * PLANE)   // elems per tensor in kqv buf

typedef __attribute__((ext_vector_type(8))) short  short8;   // 8 bf16 = 4 VGPR
typedef __attribute__((ext_vector_type(4))) float  float4v;  // MFMA C/D

__device__ __forceinline__ unsigned short f2b(float f) {
    __hip_bfloat16 h = __float2bfloat16(f);
    return *reinterpret_cast<unsigned short*>(&h);
}
__device__ __forceinline__ unsigned packbf(float lo, float hi) {
    return (unsigned)f2b(lo) | ((unsigned)f2b(hi) << 16);
}
__device__ __forceinline__ float bf2f(unsigned short u) {
    union { unsigned i; float f; } x; x.i = ((unsigned)u) << 16; return x.f;
}

// ---------------------------------------------------------------------------
// Prep: weights -> bf16 wbf[o'][c] (o' = tensor*128+o, c contiguous = natural
// A-fragment layout), biases -> f32 bias[384].
// ---------------------------------------------------------------------------
__global__ void prep_kernel(const float* __restrict__ wk, const float* __restrict__ bk,
                            const float* __restrict__ wq, const float* __restrict__ bq,
                            const float* __restrict__ wv, const float* __restrict__ bv,
                            unsigned short* __restrict__ wbf, float* __restrict__ bias)
{
    int i = blockIdx.x * 256 + threadIdx.x;   // 0..49151
    int tensor = i >> 14, oc = i & 16383;
    const float* w = tensor == 0 ? wk : (tensor == 1 ? wq : wv);
    wbf[i] = f2b(w[oc]);
    if (i < 384) {
        const float* b = i < 128 ? bk : (i < 256 ? bq : bv);
        bias[i] = b[i & 127];
    }
}

// ---------------------------------------------------------------------------
// Phase A (MFMA): kqv[o'][n][ch][hw] bf16 = W[o'][c] x X[c][hw] + bias.
// Block: 256 thr, 64-hw tile. X tile staged to LDS transposed [hw][c] bf16
// (row stride 68 uints -> b128 read/write bank-balanced). Waves split the 384
// output rows (96 each); W fragments are 16B/lane loads from L2-hot wbf.
// ---------------------------------------------------------------------------
__global__ __launch_bounds__(256) void kqv_kernel(
    const float* __restrict__ x, const unsigned short* __restrict__ wbf,
    const float* __restrict__ bias, unsigned short* __restrict__ kqv)
{
    __shared__ unsigned Xl[64 * 68];   // [hw][c/2], 17 KiB

    const int n   = blockIdx.y;
    const int hw0 = blockIdx.x * 64;
    const int t    = threadIdx.x;
    const int lane = t & 63, wv = t >> 6;
    const int l15  = lane & 15, quad = lane >> 4;

    // ---- stage x tile (fp32 [c][hw] -> bf16 LDS [hw][c]) ----
    const float* xp = x + (size_t)n * PLANE + hw0 + lane;
    #pragma unroll
    for (int it = 0; it < 4; ++it) {
        const int c0 = (wv * 4 + it) * 8;
        float v[8];
        #pragma unroll
        for (int j = 0; j < 8; ++j) v[j] = xp[(size_t)(c0 + j) * HWN];
        uint4 u;
        u.x = packbf(v[0], v[1]); u.y = packbf(v[2], v[3]);
        u.z = packbf(v[4], v[5]); u.w = packbf(v[6], v[7]);
        *(uint4*)&Xl[lane * 68 + c0 / 2] = u;
    }
    __syncthreads();

    // ---- B fragments (all 4 hw n-tiles x 4 k-steps), hoisted ----
    short8 bfr[4][4];
    #pragma unroll
    for (int nt = 0; nt < 4; ++nt)
        #pragma unroll
        for (int k = 0; k < 4; ++k)
            bfr[nt][k] = *(const short8*)&Xl[(nt * 16 + l15) * 68 + quad * 4 + k * 16];

    // ---- 6 m-tiles of 16 output rows per wave ----
    for (int mt = 0; mt < 6; ++mt) {
        const int o0 = wv * 96 + mt * 16;
        short8 afr[4];
        #pragma unroll
        for (int k = 0; k < 4; ++k)
            afr[k] = *(const short8*)&wbf[(o0 + l15) * CN + quad * 8 + k * 32];
        float b0 = bias[o0 + quad * 4 + 0], b1 = bias[o0 + quad * 4 + 1];
        float b2 = bias[o0 + quad * 4 + 2], b3 = bias[o0 + quad * 4 + 3];

        #pragma unroll
        for (int nt = 0; nt < 4; ++nt) {
            float4v acc = {b0, b1, b2, b3};
            #pragma unroll
            for (int k = 0; k < 4; ++k)
                acc = __builtin_amdgcn_mfma_f32_16x16x32_bf16(afr[k], bfr[nt][k], acc, 0, 0, 0);
            #pragma unroll
            for (int r = 0; r < 4; ++r) {
                const int oo = o0 + quad * 4 + r;   // 0..383
                const size_t idx = (size_t)(oo >> 7) * TSTRIDE
                                 + ((size_t)n * CN + (oo & 127)) * HWN
                                 + hw0 + nt * 16 + l15;
                kqv[idx] = f2b(acc[r]);
            }
        }
    }
}

// ---------------------------------------------------------------------------
// Phase B (MFMA): per (n,o) block (256 thr):
//   GEMM1: S^T[v][w] = sum_h Qt[v][h]*Kt[w][h]  (Kt/Qt = LDS transposes)
//   softmax over w, entirely in registers (in-lane + quad shfl_xor)
//   attn^T bf16 -> LDS (aliases dead Kt)
//   GEMM2: O[h][v] = sum_w V[h][w]*attnT[v][w];  out = gamma*O + x
// LDS 68 KiB -> 2 blocks/CU.
// ---------------------------------------------------------------------------
__global__ __launch_bounds__(256) void attn_kernel(
    const unsigned short* __restrict__ kqv, const float* __restrict__ x,
    const float* __restrict__ gamma, float* __restrict__ out)
{
    __shared__ unsigned lds[17408];          // Kt[0:8704) Qt[8704:17408), 68 KiB
    unsigned* Kt = lds;                      // [w][h/2], stride 68 uints
    unsigned* Qt = lds + 8704;               // [v][h/2]
    unsigned short* At = (unsigned short*)lds;  // attn^T [v][w], stride 136 halves (34 KiB, aliases Kt)

    const int no = blockIdx.x;
    const unsigned short* Kg = kqv + (size_t)no * HWN;
    const unsigned short* Qg = Kg + TSTRIDE;
    const unsigned short* Vg = Kg + 2 * TSTRIDE;

    const int t = threadIdx.x, lane = t & 63, wv = t >> 6;
    const int l15 = lane & 15, quad = lane >> 4;

    // ---- stage Kt[w][h], Qt[v][h] (global bf16 [h][w] -> LDS transposed) ----
    #pragma unroll
    for (int p = 0; p < 8; ++p) {
        const int w  = (p & 1) * 64 + lane;
        const int h0 = ((p >> 1) * 4 + wv) * 8;
        unsigned short kv[8], qv[8];
        #pragma unroll
        for (int j = 0; j < 8; ++j) {
            kv[j] = Kg[(h0 + j) * 128 + w];
            qv[j] = Qg[(h0 + j) * 128 + w];
        }
        uint4 a, b;
        a.x = (unsigned)kv[0] | ((unsigned)kv[1] << 16); a.y = (unsigned)kv[2] | ((unsigned)kv[3] << 16);
        a.z = (unsigned)kv[4] | ((unsigned)kv[5] << 16); a.w = (unsigned)kv[6] | ((unsigned)kv[7] << 16);
        b.x = (unsigned)qv[0] | ((unsigned)qv[1] << 16); b.y = (unsigned)qv[2] | ((unsigned)qv[3] << 16);
        b.z = (unsigned)qv[4] | ((unsigned)qv[5] << 16); b.w = (unsigned)qv[6] | ((unsigned)qv[7] << 16);
        *(uint4*)&Kt[w * 68 + h0 / 2] = a;
        *(uint4*)&Qt[w * 68 + h0 / 2] = b;
    }
    __syncthreads();

    // ---- GEMM1: wave handles v-strip of 32 (2 m-tiles x 8 n-tiles x 4 k) ----
    const int v0 = wv * 32;
    float4v acc1[2][8];
    #pragma unroll
    for (int mt = 0; mt < 2; ++mt)
        #pragma unroll
        for (int nt = 0; nt < 8; ++nt) acc1[mt][nt] = (float4v){0.f, 0.f, 0.f, 0.f};

    {
        short8 afr[2][4];
        #pragma unroll
        for (int mt = 0; mt < 2; ++mt)
            #pragma unroll
            for (int k = 0; k < 4; ++k)
                afr[mt][k] = *(const short8*)&Qt[(v0 + mt * 16 + l15) * 68 + quad * 4 + k * 16];
        #pragma unroll
        for (int nt = 0; nt < 8; ++nt) {
            short8 bfr[4];
            #pragma unroll
            for (int k = 0; k < 4; ++k)
                bfr[k] = *(const short8*)&Kt[(nt * 16 + l15) * 68 + quad * 4 + k * 16];
            #pragma unroll
            for (int mt = 0; mt < 2; ++mt)
                #pragma unroll
                for (int k = 0; k < 4; ++k)
                    acc1[mt][nt] = __builtin_amdgcn_mfma_f32_16x16x32_bf16(afr[mt][k], bfr[k], acc1[mt][nt], 0, 0, 0);
        }
    }
    __syncthreads();   // all waves done reading Kt/Qt; At may now overwrite Kt

    // ---- softmax over w (rows of S^T), in registers ----
    const float sc = 0.08838834764831845f;   // 1/sqrt(128)
    #pragma unroll
    for (int mt = 0; mt < 2; ++mt)
        #pragma unroll
        for (int r = 0; r < 4; ++r) {
            float m = -INFINITY;
            #pragma unroll
            for (int nt = 0; nt < 8; ++nt) {
                acc1[mt][nt][r] *= sc;
                m = fmaxf(m, acc1[mt][nt][r]);
            }
            #pragma unroll
            for (int d = 1; d < 16; d <<= 1) m = fmaxf(m, __shfl_xor(m, d, 64));
            float s = 0.f;
            #pragma unroll
            for (int nt = 0; nt < 8; ++nt) {
                const float e = __expf(acc1[mt][nt][r] - m);
                acc1[mt][nt][r] = e;
                s += e;
            }
            #pragma unroll
            for (int d = 1; d < 16; d <<= 1) s += __shfl_xor(s, d, 64);
            const float inv = 1.0f / s;
            const int v = v0 + mt * 16 + quad * 4 + r;
            #pragma unroll
            for (int nt = 0; nt < 8; ++nt)
                At[v * 136 + nt * 16 + l15] = f2b(acc1[mt][nt][r] * inv);
        }
    __syncthreads();

    // ---- GEMM2: O[h][v], wave handles h-strip of 32 ----
    const int h0 = wv * 32;
    float4v acc2[2][8];
    #pragma unroll
    for (int mt = 0; mt < 2; ++mt)
        #pragma unroll
        for (int nt = 0; nt < 8; ++nt) acc2[mt][nt] = (float4v){0.f, 0.f, 0.f, 0.f};

    {
        short8 vfr[2][4];   // V fragments straight from global (w-contiguous)
        #pragma unroll
        for (int mt = 0; mt < 2; ++mt)
            #pragma unroll
            for (int k = 0; k < 4; ++k)
                vfr[mt][k] = *(const short8*)&Vg[(h0 + mt * 16 + l15) * 128 + quad * 8 + k * 32];
        #pragma unroll
        for (int nt = 0; nt < 8; ++nt) {
            short8 bfr[4];
            #pragma unroll
            for (int k = 0; k < 4; ++k)
                bfr[k] = *(const short8*)&At[(nt * 16 + l15) * 136 + quad * 8 + k * 32];
            #pragma unroll
            for (int mt = 0; mt < 2; ++mt)
                #pragma unroll
                for (int k = 0; k < 4; ++k)
                    acc2[mt][nt] = __builtin_amdgcn_mfma_f32_16x16x32_bf16(vfr[mt][k], bfr[k], acc2[mt][nt], 0, 0, 0);
        }
    }

    // ---- epilogue: out = gamma*O + x ----
    const float g = gamma[0];
    const float* xp = x + (size_t)no * HWN;
    float*       op = out + (size_t)no * HWN;
    #pragma unroll
    for (int mt = 0; mt < 2; ++mt)
        #pragma unroll
        for (int nt = 0; nt < 8; ++nt)
            #pragma unroll
            for (int r = 0; r < 4; ++r) {
                const int h = h0 + mt * 16 + quad * 4 + r;
                const int v = nt * 16 + l15;
                const int idx = h * 128 + v;
                op[idx] = fmaf(g, acc2[mt][nt][r], xp[idx]);
            }
}

// ---------------------------------------------------------------------------
extern "C" void kernel_launch(void* const* d_in, const int* in_sizes, int n_in,
                              void* d_out, int out_size, void* d_ws, size_t ws_size,
                              hipStream_t stream) {
    const float* x     = (const float*)d_in[0];
    const float* wk    = (const float*)d_in[1];
    const float* bk    = (const float*)d_in[2];
    const float* wq    = (const float*)d_in[3];
    const float* bq    = (const float*)d_in[4];
    const float* wv    = (const float*)d_in[5];
    const float* bv    = (const float*)d_in[6];
    const float* gamma = (const float*)d_in[7];
    float* out = (float*)d_out;

    // ws: wbf bf16 (96 KiB) | bias f32 (1.5 KiB) ... | kqv bf16 @ 256 KiB (192 MiB)
    unsigned short* wbf  = (unsigned short*)d_ws;
    float*          bias = (float*)((char*)d_ws + (192 << 10));
    unsigned short* kqv  = (unsigned short*)((char*)d_ws + (256 << 10));

    prep_kernel<<<192, 256, 0, stream>>>(wk, bk, wq, bq, wv, bv, wbf, bias);
    dim3 gA(HWN / 64, NBATCH);
    kqv_kernel<<<gA, 256, 0, stream>>>(x, wbf, bias, kqv);
    attn_kernel<<<NBATCH * CN, 256, 0, stream>>>(kqv, x, gamma, out);
}